// Round 5
// baseline (535.175 us; speedup 1.0000x reference)
//
#include <hip/hip_runtime.h>

typedef __attribute__((ext_vector_type(8))) _Float16 half8;
typedef __attribute__((ext_vector_type(4))) float f32x4;
typedef __attribute__((ext_vector_type(16))) float f32x16;

__device__ __forceinline__ void gll16(const void* g, void* l) {
  __builtin_amdgcn_global_load_lds(
      (const __attribute__((address_space(1))) unsigned int*)g,
      (__attribute__((address_space(3))) unsigned int*)l, 16, 0, 0);
}

// ---- fused LayerNorm: one ROW PER WAVE; lane owns 16 CONTIGUOUS elems ----
// All global loads and stores are 16B/lane full-width.
// tasks 0..4095 : feat->q16 | 4096..36863 : mem_k->k16 | 36864..69631 : mem_v->v8
__global__ __launch_bounds__(256) void ln_fused(
    const float* __restrict__ feat, const float* __restrict__ mem_k,
    const float* __restrict__ mem_v, const float* __restrict__ g_q,
    const float* __restrict__ b_q, const float* __restrict__ g_k,
    const float* __restrict__ b_k, const float* __restrict__ g_v,
    const float* __restrict__ b_v, _Float16* __restrict__ q16,
    _Float16* __restrict__ k16, char* __restrict__ v8,
    float* __restrict__ vscale) {
  const int C = 1024;
  int wave = threadIdx.x >> 6, lane = threadIdx.x & 63;
  int task = blockIdx.x * 4 + wave;

  const float *x, *g, *b;
  int mode;
  size_t row;
  if (task < 4096) {
    x = feat; g = g_q; b = b_q; mode = 0; row = task;
  } else if (task < 36864) {
    x = mem_k; g = g_k; b = b_k; mode = 1; row = task - 4096;
  } else {
    x = mem_v; g = g_v; b = b_v; mode = 2; row = task - 36864;
  }

  const float4* xr = (const float4*)(x + row * C + lane * 16);
  float4 v[4];
  float s = 0.f, s2 = 0.f;
#pragma unroll
  for (int j = 0; j < 4; ++j) {
    v[j] = xr[j];
    s += v[j].x + v[j].y + v[j].z + v[j].w;
    s2 += v[j].x * v[j].x + v[j].y * v[j].y + v[j].z * v[j].z + v[j].w * v[j].w;
  }
#pragma unroll
  for (int off = 1; off < 64; off <<= 1) {
    s += __shfl_xor(s, off, 64);
    s2 += __shfl_xor(s2, off, 64);
  }
  float mu = s * (1.0f / C);
  float var = s2 * (1.0f / C) - mu * mu;
  float rstd = rsqrtf(var + 1e-5f);

  const float4* gr = (const float4*)(g + lane * 16);
  const float4* br = (const float4*)(b + lane * 16);
  float y[16];
#pragma unroll
  for (int j = 0; j < 4; ++j) {
    float4 gv = gr[j];
    float4 bv = br[j];
    y[4 * j + 0] = (v[j].x - mu) * rstd * gv.x + bv.x;
    y[4 * j + 1] = (v[j].y - mu) * rstd * gv.y + bv.y;
    y[4 * j + 2] = (v[j].z - mu) * rstd * gv.z + bv.z;
    y[4 * j + 3] = (v[j].w - mu) * rstd * gv.w + bv.w;
  }

  if (mode < 2) {
    _Float16* yo = (mode == 0 ? q16 : k16) + row * C + lane * 16;
#pragma unroll
    for (int j = 0; j < 2; ++j) {
      half8 h;
#pragma unroll
      for (int c = 0; c < 8; ++c) h[c] = (_Float16)y[8 * j + c];
      ((half8*)yo)[j] = h;
    }
  } else {
    float mx = 0.f;
#pragma unroll
    for (int i = 0; i < 16; ++i) mx = fmaxf(mx, fabsf(y[i]));
#pragma unroll
    for (int off = 1; off < 64; off <<= 1) mx = fmaxf(mx, __shfl_xor(mx, off, 64));
    mx = fmaxf(mx, 1e-20f);
    float inv = 127.0f / mx;
    uint4 pk;
    unsigned w[4];
#pragma unroll
    for (int j = 0; j < 4; ++j) {
      int q0 = (int)rintf(y[4 * j + 0] * inv), q1 = (int)rintf(y[4 * j + 1] * inv);
      int q2 = (int)rintf(y[4 * j + 2] * inv), q3 = (int)rintf(y[4 * j + 3] * inv);
      w[j] = ((unsigned)(q0 & 0xff)) | ((unsigned)(q1 & 0xff) << 8) |
             ((unsigned)(q2 & 0xff) << 16) | ((unsigned)(q3 & 0xff) << 24);
    }
    pk.x = w[0]; pk.y = w[1]; pk.z = w[2]; pk.w = w[3];
    *(uint4*)(v8 + row * C + lane * 16) = pk;
    if (lane == 0) vscale[row] = mx * (1.0f / 127.0f);
  }
}

// -------- QK^T GEMM, 256x128 tile, minimum 2-phase, 2 blocks/CU --------
// 512 thr = 8 waves (2M x 4N), per-wave 128x32 out via mfma_f32_32x32x16_f16
// (acc = 4 x f32x16 = 64 VGPR -> fits 128-reg budget for 2 blocks/CU).
// BK=32, double-buffered LDS: A 2x16KB + B 2x8KB = 48 KiB. Per K-step:
// {stage next tile (3 gll16) | ds_read frags | 8 MFMA setprio | vmcnt(0) |
// one barrier}  (catalog minimum-2-phase template; 2 blocks/CU provide the
// cross-block overlap of the stage stall that 1-block/CU lacked).
// Epilogue: acc -> LDS (conf pre-scaled, f16) -> coalesced half8 row stores
// (256B contiguous per 16-lane group vs previous 2B scatter).
__global__ __launch_bounds__(512, 4) void gemm_qk_2ph(
    const _Float16* __restrict__ A,   // [B][1024][1024] q16
    const _Float16* __restrict__ Bm,  // [B][8192][1024] k16
    _Float16* __restrict__ Sm,        // [B][1024][8192]
    const float* __restrict__ conf)   // [B][8192]
{
  const int N = 8192, K = 1024;
  int bz = blockIdx.z;
  const _Float16* Ab = A + (size_t)bz * 1024 * K;
  const _Float16* Bb = Bm + (size_t)bz * (size_t)N * K;
  _Float16* Sb = Sm + (size_t)bz * 1024 * N;

  // smem: lA = 2 buf x [4 chunks][256 rows][8] = 16384 halfs (32KB)
  //       lB = 2 buf x [4 chunks][128 rows][8] =  8192 halfs (16KB)
  __shared__ _Float16 smem[16384 + 8192];
  _Float16* lA = smem;
  _Float16* lB = smem + 16384;

  int tid = threadIdx.x;
  int wave = tid >> 6, lane = tid & 63;
  int wm = wave >> 2, wn = wave & 3;   // 2 x 4 wave grid
  int lr = lane & 31, lk = lane >> 5;  // col/row-in-32, k-half
  int m0 = blockIdx.y * 256, n0 = blockIdx.x * 128;

  f32x16 acc[4];
#pragma unroll
  for (int i = 0; i < 4; ++i)
#pragma unroll
    for (int e = 0; e < 16; ++e) acc[i][e] = 0.f;

  // staging: A: thread (r=tid&255, c0=tid>>8) owns row r chunks {c0, c0+2}
  //          B: thread (rb=tid&127, cb=tid>>7) owns row rb chunk cb
  int r = tid & 255, c0 = tid >> 8;
  int rb = tid & 127, cb = tid >> 7;
  const _Float16* gA = Ab + (size_t)(m0 + r) * K + c0 * 8;
  const _Float16* gB = Bb + (size_t)(n0 + rb) * K + cb * 8;
  int dA0 = c0 * 2048 + r * 8, dA1 = (c0 + 2) * 2048 + r * 8;
  int dB = cb * 1024 + rb * 8;

  auto stage = [&](int t) {
    int pA = (t & 1) * 8192, pB = (t & 1) * 4096;
    const _Float16* ga = gA + t * 32;
    gll16(ga, &lA[pA + dA0]);
    gll16(ga + 16, &lA[pA + dA1]);
    gll16(gB + t * 32, &lB[pB + dB]);
  };

  auto compute = [&](int p) {
    int pA = p * 8192, pB = p * 4096;
#pragma unroll
    for (int ks = 0; ks < 2; ++ks) {
      const _Float16* la = &lA[pA + (ks * 2 + lk) * 2048 + (wm * 128 + lr) * 8];
      const _Float16* lb = &lB[pB + (ks * 2 + lk) * 1024 + (wn * 32 + lr) * 8];
      half8 a0 = *(const half8*)(la);
      half8 a1 = *(const half8*)(la + 256);   // +32 rows
      half8 a2 = *(const half8*)(la + 512);
      half8 a3 = *(const half8*)(la + 768);
      half8 b0 = *(const half8*)(lb);
      __builtin_amdgcn_s_setprio(1);
      acc[0] = __builtin_amdgcn_mfma_f32_32x32x16_f16(a0, b0, acc[0], 0, 0, 0);
      acc[1] = __builtin_amdgcn_mfma_f32_32x32x16_f16(a1, b0, acc[1], 0, 0, 0);
      acc[2] = __builtin_amdgcn_mfma_f32_32x32x16_f16(a2, b0, acc[2], 0, 0, 0);
      acc[3] = __builtin_amdgcn_mfma_f32_32x32x16_f16(a3, b0, acc[3], 0, 0, 0);
      __builtin_amdgcn_s_setprio(0);
    }
  };

  // prologue
  stage(0);
  __builtin_amdgcn_s_waitcnt(0xF70);  // vmcnt(0)
  __builtin_amdgcn_s_barrier();
  __builtin_amdgcn_sched_barrier(0);

  // main loop: one barrier per K-step (minimum 2-phase template)
#pragma unroll 1
  for (int t = 0; t < 31; ++t) {
    stage(t + 1);        // into buf (t+1)&1 (disjoint from compute buf)
    compute(t & 1);
    __builtin_amdgcn_sched_barrier(0);
    __builtin_amdgcn_s_waitcnt(0xF70);  // vmcnt(0): stage(t+1) landed
    __builtin_amdgcn_s_barrier();
    __builtin_amdgcn_sched_barrier(0);
  }
  compute(1);  // tile 31

  // ---- epilogue: coalesced S stores via LDS transpose ----
  // acc[mf][rr] = C[row_l][col_l], row_l = wm*128 + mf*32 + (rr&3)+8*(rr>>2)+4*lk,
  // col_l = wn*32 + lr (lane-constant -> conf scale per lane).
  __syncthreads();
  _Float16* ep = smem;  // 128 x 130 halfs = 16640 <= 24576
  int gnl = wn * 32 + lr;
  float cs = 0.03125f * conf[(size_t)bz * N + n0 + gnl];
#pragma unroll 1
  for (int h = 0; h < 2; ++h) {
    if (wm == h) {
#pragma unroll
      for (int mf = 0; mf < 4; ++mf)
#pragma unroll
        for (int rr = 0; rr < 16; ++rr) {
          int rloc = mf * 32 + (rr & 3) + 8 * (rr >> 2) + 4 * lk;
          ep[rloc * 130 + gnl] = (_Float16)(acc[mf][rr] * cs);
        }
    }
    __syncthreads();
#pragma unroll
    for (int it = 0; it < 4; ++it) {
      int rloc = (tid >> 4) + 32 * it;
      int ch = tid & 15;
      half8 hv = *(const half8*)&ep[rloc * 130 + ch * 8];
      *(half8*)&Sb[(size_t)(m0 + h * 128 + rloc) * N + n0 + ch * 8] = hv;
    }
    __syncthreads();
  }
}

__device__ __forceinline__ float h2f(unsigned short hb) {
  _Float16 h;
  __builtin_memcpy(&h, &hb, 2);
  return (float)h;
}

__device__ __forceinline__ void acc4(float* a, unsigned w, float wt) {
  a[0] += wt * (float)(signed char)(w & 0xff);
  a[1] += wt * (float)(signed char)((w >> 8) & 0xff);
  a[2] += wt * (float)(signed char)((w >> 16) & 0xff);
  a[3] += wt * (float)(signed char)(w >> 24);
}

// ---- fused softmax + threshold + renorm + compact(LDS) + sparse gather ----
// One block (512 thr) per output row. cnt <= 2000 provably (w >= 0.0005*sum).
__global__ __launch_bounds__(512) void softmax_gather(
    const _Float16* __restrict__ S, const char* __restrict__ v8,
    const float* __restrict__ vscale, const float* __restrict__ feat,
    float* __restrict__ out) {
  const int X = 8192, C = 1024;
  int row = blockIdx.x;  // b*1024 + p
  int b = row >> 10;
  int t = threadIdx.x;
  int wave = t >> 6, lane = t & 63;

  __shared__ float sh[8];
  __shared__ int scnt;
  __shared__ unsigned short sx[2048];
  __shared__ float sw[2048];
  __shared__ float red[8][1028];

  const half8* sr = (const half8*)(S + (size_t)row * X);
  float v[16];
#pragma unroll
  for (int j = 0; j < 2; ++j) {
    half8 h = sr[t + j * 512];
#pragma unroll
    for (int c = 0; c < 8; ++c) v[j * 8 + c] = (float)h[c];
  }

  float m = -1e30f;
#pragma unroll
  for (int i = 0; i < 16; ++i) m = fmaxf(m, v[i]);
#pragma unroll
  for (int off = 1; off < 64; off <<= 1) m = fmaxf(m, __shfl_xor(m, off, 64));
  if (lane == 0) sh[wave] = m;
  __syncthreads();
  m = fmaxf(fmaxf(fmaxf(sh[0], sh[1]), fmaxf(sh[2], sh[3])),
            fmaxf(fmaxf(sh[4], sh[5]), fmaxf(sh[6], sh[7])));
  __syncthreads();

  float l = 0.f;
#pragma unroll
  for (int i = 0; i < 16; ++i) {
    v[i] = __expf(v[i] - m);
    l += v[i];
  }
#pragma unroll
  for (int off = 1; off < 64; off <<= 1) l += __shfl_xor(l, off, 64);
  if (lane == 0) sh[wave] = l;
  __syncthreads();
  l = sh[0] + sh[1] + sh[2] + sh[3] + sh[4] + sh[5] + sh[6] + sh[7];
  __syncthreads();

  float thr = 0.0005f * l;
  float ks = 0.f;
#pragma unroll
  for (int i = 0; i < 16; ++i) {
    v[i] = (v[i] >= thr) ? v[i] : 0.f;
    ks += v[i];
  }
#pragma unroll
  for (int off = 1; off < 64; off <<= 1) ks += __shfl_xor(ks, off, 64);
  if (lane == 0) sh[wave] = ks;
  if (t == 0) scnt = 0;
  __syncthreads();
  ks = sh[0] + sh[1] + sh[2] + sh[3] + sh[4] + sh[5] + sh[6] + sh[7];

  float inv = 1.0f / ks;
  const float* sb = vscale + (size_t)b * X;
#pragma unroll
  for (int j = 0; j < 2; ++j) {
#pragma unroll
    for (int c = 0; c < 8; ++c) {
      float val = v[j * 8 + c];
      if (val > 0.f) {
        int pos = atomicAdd(&scnt, 1);
        int x = (t + j * 512) * 8 + c;
        sx[pos] = (unsigned short)x;
        sw[pos] = val * inv * sb[x];
      }
    }
  }
  __syncthreads();
  int cnt = scnt;

  const char* vb = v8 + (size_t)b * X * C;
  int cby = lane * 16;
  float a[16];
#pragma unroll
  for (int i = 0; i < 16; ++i) a[i] = 0.f;

#pragma unroll 4
  for (int j = wave; j < cnt; j += 8) {
    int x = sx[j];
    float w = sw[j];
    uint4 pv = *(const uint4*)(vb + (size_t)x * C + cby);
    acc4(a + 0, pv.x, w);
    acc4(a + 4, pv.y, w);
    acc4(a + 8, pv.z, w);
    acc4(a + 12, pv.w, w);
  }
  float* rp = &red[wave][cby];
#pragma unroll
  for (int i = 0; i < 16; ++i) rp[i] = a[i];
  __syncthreads();

  int p = t * 2;
  float2 f = *(const float2*)(feat + (size_t)row * C + p);
  float o0 = f.x, o1 = f.y;
#pragma unroll
  for (int ss = 0; ss < 8; ++ss) {
    o0 += red[ss][p];
    o1 += red[ss][p + 1];
  }
  float2 o = {o0, o1};
  *(float2*)(out + (size_t)row * C + p) = o;
}

extern "C" void kernel_launch(void* const* d_in, const int* in_sizes, int n_in,
                              void* d_out, int out_size, void* d_ws, size_t ws_size,
                              hipStream_t stream) {
  const int B = 4, P = 1024, X = 8192, C = 1024;
  const float* feat  = (const float*)d_in[0];
  const float* mem_k = (const float*)d_in[1];
  const float* mem_v = (const float*)d_in[2];
  const float* mem_c = (const float*)d_in[3];  // [B,X,1] -> flat [B*X]
  const float* g_q = (const float*)d_in[5];
  const float* b_q = (const float*)d_in[6];
  const float* g_k = (const float*)d_in[7];
  const float* b_k = (const float*)d_in[8];
  const float* g_v = (const float*)d_in[9];
  const float* b_v = (const float*)d_in[10];

  char* ws = (char*)d_ws;
  const size_t MB = 1024 * 1024;
  _Float16* q16 = (_Float16*)(ws + 0);             // 8 MB   [B][P][C]
  _Float16* k16 = (_Float16*)(ws + 8 * MB);        // 64 MB  [B][X][C]
  _Float16* S   = (_Float16*)(ws + 72 * MB);       // 64 MB  [B][P][X]
  char*     v8  = (char*)(ws + 136 * MB);          // 32 MB  [B][X][C] int8
  float* vscale = (float*)(ws + 168 * MB);         // 128 KB [B*X]

  ln_fused<<<(4096 + 32768 + 32768) / 4, 256, 0, stream>>>(
      feat, mem_k, mem_v, g_q, b_q, g_k, b_k, g_v, b_v, q16, k16, v8, vscale);
  gemm_qk_2ph<<<dim3(X / 128, P / 256, B), 512, 0, stream>>>(q16, k16, S, mem_c);
  softmax_gather<<<B * P, 512, 0, stream>>>(S, v8, vscale, feat, (float*)d_out);
}